// Round 6
// baseline (58724.487 us; speedup 1.0000x reference)
//
#include <hip/hip_runtime.h>

// PRPN eval forward for MI355X. All float inputs are FP32, ids int32.
// Output = [y (T*B*D) | mask (T*B)] fp32.
//
// R11: recurrent cycles are fully wg-local (no cross-wg hop on any cycle).
//  - L0/L1 waves compute their own fresh-P (whh @ h_new, 1536 cols) and
//    key_mh (proj_mh @ h_new, 384 cols) locally each step; the P mirror and
//    key become wave-private. L0 has NO blocking wait (only a lagged ring
//    guard); L1 consumes feed-forward IH1RAW/KEY1H from G0 (ring-4).
//  - PR computes pkey locally (pproj@h1(t) + pproj_m@h1(t-1)) -> G1 class
//    eliminated.
//  - G0 (32 wgs x 60 cols) computes only feed-forward wih1/proj1h from
//    h0(t) into ring-4 buffers; off the critical cycle.
//  - Rings depth 4 (HNEW0, HNEW1, IH1RAW, KEY1H) with lagged t-3 guards:
//    L0(t): G0F>=t-3 | G0(t): L0F>=t+1, L1F>=t-3 | L1(t): G0F>=t+1, PRF>=t-3
//    PR(t): L1F>=t+1.  All waits are on strictly earlier completions.
//  - Local GEMV: lane=(cs,kg)=8x8, k-chunks of 48, xr[48] from LDS, shfl-xor
//    reduce (same association as old gemv_run -> bitwise-compatible).
//  - Grid: 8 L0 + 8 L1 + 8 PR + 32 G0 = 56 wgs.

#define TT 192
#define TB 6144

constexpr size_t O_EMB    = 0;          // T*B*384 fp32
constexpr size_t O_IH0LN  = 2359296;    // T*B*1536 (raw then LN'd in place)
constexpr size_t O_KEY0E  = 11796480;   // T*B*384
constexpr size_t O_MG     = 14155776;   // T*B*15
constexpr size_t O_MGN    = 14247936;   // T*B*15
// ---- dead conv-activation region reused for scan exchange buffers ----
constexpr size_t O_H1      = 14340096;  // B*T x 384 conv acts (pre-scan only)
constexpr size_t O_HNEW0R  = 14340096;  // [4][32][384] ring
constexpr size_t O_HNEW1R  = 14389248;  // [4][32][384] ring
constexpr size_t O_IH1RAWR = 14438400;  // [4][32][1536] ring
constexpr size_t O_KEY1HR  = 14635008;  // [4][32][384] ring
constexpr size_t O_BAR     = 14684160;  // flags (1024 u32)
constexpr size_t O_DEADEND = 14685184;
// ---------------------------------------------------------------------
constexpr size_t O_GATEA  = 16699392;   // B*T
constexpr size_t O_GATEB  = 16705536;   // B*T
constexpr size_t O_OUTHS  = 16711680;   // T*B x 768 (h | sel)
constexpr size_t O_MEMH0  = 21430272;   // state (zeroed): B x 15 x 384 each
constexpr size_t O_MEMC0  = 21614592;
constexpr size_t O_MEMH1  = 21798912;
constexpr size_t O_MEMC1  = 21983232;
constexpr size_t O_PMEM   = 22167552;
constexpr size_t O_P0     = 22351872;   // P0 mirror: B x 15 x 1536 (wave-private)
constexpr size_t O_P1     = 23089152;   // P1 mirror
constexpr size_t O_STATEEND = 23826432;

// packed flag arrays (u32 index inside BAR)
#define F_L0  0      // [32] per-b
#define F_L1  32     // [32]
#define F_PR  64     // [32]
#define F_G0  96     // [32] per G0 wg

__device__ __forceinline__ float sigmoidf(float x) { return 1.f / (1.f + expf(-x)); }

// LLC-coherent relaxed accessors for cross-wg exchange.
__device__ __forceinline__ float ldx(const float* p) {
  return __hip_atomic_load(p, __ATOMIC_RELAXED, __HIP_MEMORY_SCOPE_AGENT);
}
__device__ __forceinline__ void stx(float* p, float v) {
  __hip_atomic_store(p, v, __ATOMIC_RELAXED, __HIP_MEMORY_SCOPE_AGENT);
}
__device__ __forceinline__ float2 ldx2(const float* p) {
  unsigned long long v = __hip_atomic_load((const unsigned long long*)p,
                                           __ATOMIC_RELAXED, __HIP_MEMORY_SCOPE_AGENT);
  return __builtin_bit_cast(float2, v);
}
__device__ __forceinline__ void stx2(float* p, float2 v) {
  __hip_atomic_store((unsigned long long*)p, __builtin_bit_cast(unsigned long long, v),
                     __ATOMIC_RELAXED, __HIP_MEMORY_SCOPE_AGENT);
}
__device__ __forceinline__ int ldi(const int* p) {
  return __hip_atomic_load(p, __ATOMIC_RELAXED, __HIP_MEMORY_SCOPE_AGENT);
}
__device__ __forceinline__ void sti(int* p, int v) {
  __hip_atomic_store(p, v, __ATOMIC_RELAXED, __HIP_MEMORY_SCOPE_AGENT);
}

constexpr float BN_SC = 0.9999950000374997f;       // 1/sqrt(1+1e-5)
constexpr float INV_SQRT_H = 0.05103103630798288f; // 1/sqrt(384)

__device__ __forceinline__ float blockSum(float v, float* red) {
#pragma unroll
  for (int off = 32; off > 0; off >>= 1) v += __shfl_down(v, off, 64);
  __syncthreads();
  if ((threadIdx.x & 63) == 0) red[threadIdx.x >> 6] = v;
  __syncthreads();
  return red[0] + red[1] + red[2] + red[3];
}

__device__ __forceinline__ float2 wred2(float a, float b) {
#pragma unroll
  for (int off = 32; off > 0; off >>= 1) {
    a += __shfl_xor(a, off, 64);
    b += __shfl_xor(b, off, 64);
  }
  return make_float2(a, b);
}

__device__ __forceinline__ float dot48(const float* wr, const float* xr) {
  float a = 0.f;
#pragma unroll
  for (int q = 0; q < 12; ++q) {
    float4 w = *(const float4*)(wr + q * 4);
    a += w.x * xr[q * 4 + 0] + w.y * xr[q * 4 + 1]
       + w.z * xr[q * 4 + 2] + w.w * xr[q * 4 + 3];
  }
  return a;
}
__device__ __forceinline__ float red8(float a) {
  a += __shfl_xor(a, 1, 64); a += __shfl_xor(a, 2, 64); a += __shfl_xor(a, 4, 64);
  return a;
}

// ---------------------------------------------------------------- k_zero
__global__ __launch_bounds__(256) void k_zero(float* p, int n) {
  int i = blockIdx.x * 256 + threadIdx.x;
  int stride = gridDim.x * 256;
  for (; i < n; i += stride) p[i] = 0.f;
}

// ---------------------------------------------------------------- k_emb (+mask)
__global__ __launch_bounds__(256) void k_emb(const int* ids, const float* emb_w,
                                             float* emb, float* out) {
  size_t idx = (size_t)blockIdx.x * 256 + threadIdx.x;
  size_t stride = (size_t)gridDim.x * 256;
  for (size_t i = idx; i < (size_t)TB * 384; i += stride) {
    size_t tb = i / 384, d = i - tb * 384;
    int id = ids[tb];
    emb[i] = emb_w[(size_t)id * 384 + d];
    if (i < TB) out[(size_t)TB * 384 + i] = (ids[i] != 0) ? 1.f : 0.f;
  }
}

// ---------------------------------------------------------------- k_conv (im2col GEMM)
__global__ __launch_bounds__(256) void k_conv(const float* emb, const float* W1, const float* cbias,
                                              const float* bng, const float* bnb, float* h1) {
  __shared__ float As[32][68];
  __shared__ float Bs[32][68];
  int n0 = blockIdx.x * 64, m0 = blockIdx.y * 64;
  int tid = threadIdx.x;
  float acc[4][4] = {};
  int mi = tid >> 3, kq = tid & 7;
  int ni = tid >> 2, kb = tid & 3;
  for (int kk = 0; kk < 2304; kk += 32) {
    int kc = kk / 384, dbase = kk - kc * 384;
    __syncthreads();
#pragma unroll
    for (int p = 0; p < 2; ++p) {
      int m = m0 + mi + 32 * p;
      int b = m / 192, t = m - b * 192;
      int tt = t + kc - 5;
      float4 v = {0.f, 0.f, 0.f, 0.f};
      if (tt >= 0) v = *(const float4*)(emb + ((size_t)tt * 32 + b) * 384 + dbase + kq * 4);
      As[kq * 4 + 0][mi + 32 * p] = v.x; As[kq * 4 + 1][mi + 32 * p] = v.y;
      As[kq * 4 + 2][mi + 32 * p] = v.z; As[kq * 4 + 3][mi + 32 * p] = v.w;
    }
#pragma unroll
    for (int i = 0; i < 8; ++i) {
      int d = dbase + kb * 8 + i;
      Bs[kb * 8 + i][ni] = W1[(size_t)(n0 + ni) * 2304 + d * 6 + kc];
    }
    __syncthreads();
    int ty = tid >> 4, tx = tid & 15;
#pragma unroll
    for (int k = 0; k < 32; ++k) {
      float4 a = *(const float4*)(&As[k][ty * 4]);
      float4 bv = *(const float4*)(&Bs[k][tx * 4]);
      acc[0][0] += a.x * bv.x; acc[0][1] += a.x * bv.y; acc[0][2] += a.x * bv.z; acc[0][3] += a.x * bv.w;
      acc[1][0] += a.y * bv.x; acc[1][1] += a.y * bv.y; acc[1][2] += a.y * bv.z; acc[1][3] += a.y * bv.w;
      acc[2][0] += a.z * bv.x; acc[2][1] += a.z * bv.y; acc[2][2] += a.z * bv.z; acc[2][3] += a.z * bv.w;
      acc[3][0] += a.w * bv.x; acc[3][1] += a.w * bv.y; acc[3][2] += a.w * bv.z; acc[3][3] += a.w * bv.w;
    }
  }
  int ty = tid >> 4, tx = tid & 15;
#pragma unroll
  for (int i = 0; i < 4; ++i) {
    int m = m0 + ty * 4 + i;
#pragma unroll
    for (int j = 0; j < 4; ++j) {
      int n = n0 + tx * 4 + j;
      float v = acc[i][j] + cbias[n];
      v = bng[n] * v * BN_SC + bnb[n];
      h1[(size_t)m * 384 + n] = fmaxf(v, 0.f);
    }
  }
}

// ---------------------------------------------------------------- k_gate
__global__ __launch_bounds__(256) void k_gate(const float* h1, const float* w2, const float* b2,
                                              float* gA, float* gB) {
  __shared__ float red[8];
  int bt = blockIdx.x, tid = threadIdx.x;
  float v0 = 0.f, v1 = 0.f;
  if (tid < 192) {
    v0 = h1[(size_t)bt * 384 + tid] * w2[tid];
    v1 = h1[(size_t)bt * 384 + 192 + tid] * w2[192 + tid];
  }
  float s0 = blockSum(v0, red);
  float s1 = blockSum(v1, red);
  if (tid == 0) {
    gA[bt] = 1.f / (1.f + expf(-(s0 + b2[0])));
    gB[bt] = 1.f / (1.f + expf(-(s1 + b2[1])));
  }
}

// ---------------------------------------------------------------- k_mg (hard gates + cumprod)
__global__ __launch_bounds__(256) void k_mg(const float* gA, const float* gB, float* mg, float* mgn) {
  int idx = blockIdx.x * 256 + threadIdx.x;
  if (idx >= TB) return;
  int t = idx >> 5, b = idx & 31;
  float g = gA[b * 192 + t], gn = gB[b * 192 + t];
  float p = 1.f, pn = 1.f;
  for (int k = 0; k < 15; ++k) {
    float ghat = (k <= t) ? gA[b * 192 + t - k] : 1e9f;
    float u = fminf(fmaxf((g - ghat) / 0.1f * 2.f + 1.f, -1.f), 1.f);
    float un = fminf(fmaxf((gn - ghat) / 0.1f * 2.f + 1.f, -1.f), 1.f);
    p *= (u + 1.f) * 0.5f;
    pn *= (un + 1.f) * 0.5f;
    mg[(size_t)idx * 15 + k] = p;
    mgn[(size_t)idx * 15 + k] = pn;
  }
}

// ---------------------------------------------------------------- k_gemm (generic)
__global__ __launch_bounds__(256) void k_gemm(const float* A, int lda, const float* W, int ldw,
                                              const float* bias, float* Cf, int ldc, int K, int mode,
                                              const float* bng, const float* bnb, float* Cb) {
  __shared__ float As[32][68];
  __shared__ float Bs[32][68];
  int n0 = blockIdx.x * 64, m0 = blockIdx.y * 64;
  int tid = threadIdx.x;
  float acc[4][4] = {};
  int mi = tid >> 3, kq = tid & 7;
  int ni = tid >> 2, kb = tid & 3;
  for (int kk = 0; kk < K; kk += 32) {
    __syncthreads();
#pragma unroll
    for (int p = 0; p < 2; ++p) {
      int m = m0 + mi + 32 * p;
      float4 v = *(const float4*)(A + (size_t)m * lda + kk + kq * 4);
      As[kq * 4 + 0][mi + 32 * p] = v.x; As[kq * 4 + 1][mi + 32 * p] = v.y;
      As[kq * 4 + 2][mi + 32 * p] = v.z; As[kq * 4 + 3][mi + 32 * p] = v.w;
    }
    {
      const float* wp = W + (size_t)(n0 + ni) * ldw + kk + kb * 8;
      float4 q0 = *(const float4*)(wp);
      float4 q1 = *(const float4*)(wp + 4);
      Bs[kb * 8 + 0][ni] = q0.x; Bs[kb * 8 + 1][ni] = q0.y;
      Bs[kb * 8 + 2][ni] = q0.z; Bs[kb * 8 + 3][ni] = q0.w;
      Bs[kb * 8 + 4][ni] = q1.x; Bs[kb * 8 + 5][ni] = q1.y;
      Bs[kb * 8 + 6][ni] = q1.z; Bs[kb * 8 + 7][ni] = q1.w;
    }
    __syncthreads();
    int ty = tid >> 4, tx = tid & 15;
#pragma unroll
    for (int k = 0; k < 32; ++k) {
      float4 a = *(const float4*)(&As[k][ty * 4]);
      float4 bv = *(const float4*)(&Bs[k][tx * 4]);
      acc[0][0] += a.x * bv.x; acc[0][1] += a.x * bv.y; acc[0][2] += a.x * bv.z; acc[0][3] += a.x * bv.w;
      acc[1][0] += a.y * bv.x; acc[1][1] += a.y * bv.y; acc[1][2] += a.y * bv.z; acc[1][3] += a.y * bv.w;
      acc[2][0] += a.z * bv.x; acc[2][1] += a.z * bv.y; acc[2][2] += a.z * bv.z; acc[2][3] += a.z * bv.w;
      acc[3][0] += a.w * bv.x; acc[3][1] += a.w * bv.y; acc[3][2] += a.w * bv.z; acc[3][3] += a.w * bv.w;
    }
  }
  int ty = tid >> 4, tx = tid & 15;
#pragma unroll
  for (int i = 0; i < 4; ++i) {
    int m = m0 + ty * 4 + i;
#pragma unroll
    for (int j = 0; j < 4; ++j) {
      int n = n0 + tx * 4 + j;
      float v = acc[i][j];
      if (bias) v += bias[n];
      if (mode == 0) Cf[(size_t)m * ldc + n] = v;
      else Cb[(size_t)m * ldc + n] = tanhf(bng[n] * v * BN_SC + bnb[n]);
    }
  }
}

// ---------------------------------------------------------------- k_ln_rows
__global__ __launch_bounds__(256) void k_ln_rows(float* X, const float* g, const float* bt) {
  __shared__ float red[8];
  float* x = X + (size_t)blockIdx.x * 1536;
  int tid = threadIdx.x;
  float ps = 0.f;
  for (int i = tid; i < 1536; i += 256) ps += x[i];
  float mu = blockSum(ps, red) * (1.f / 1536.f);
  ps = 0.f;
  for (int i = tid; i < 1536; i += 256) { float d = x[i] - mu; ps += d * d; }
  float inv = 1.f / (sqrtf(blockSum(ps, red) * (1.f / 1535.f)) + 1e-6f);
  for (int i = tid; i < 1536; i += 256) x[i] = g[i] * (x[i] - mu) * inv + bt[i];
}

// ---------------------------------------------------------------- scan kernel
struct ScanArgs {
  float* ws;
  const float *r_whh, *r_bhh, *r_lnhh_g, *r_lnhh_b, *r_lnih_g, *r_lnih_b;
  const float *r_lnc_g, *r_lnc_b, *r_wih, *r_bih, *r_proj_w, *r_proj_b;
  const float *p_proj_w, *p_proj_b;
};

struct GJob { const float* W; int ldw; int koff; const float* bias; float* dst; int rstride; int ncols; };

__device__ __forceinline__ void resolveJob(const GJob* J, int col, const float*& W, int& ldw, int& koff,
                                           const float*& bias, float*& dst, int& rstride, int& cc) {
  int c = col;
#pragma unroll
  for (int j = 0; j < 2; ++j) {
    if (c < J[j].ncols) {
      W = J[j].W; ldw = J[j].ldw; koff = J[j].koff; bias = J[j].bias;
      dst = J[j].dst; rstride = J[j].rstride; cc = c; return;
    }
    c -= J[j].ncols;
  }
  W = J[0].W; ldw = J[0].ldw; koff = J[0].koff; bias = J[0].bias;
  dst = J[0].dst; rstride = J[0].rstride; cc = 0;
}

// stage x (32x384) into LDS [32][385] via 64-bit LLC loads
__device__ __forceinline__ void stage_x(const float* src, float* xs) {
  const int tid = threadIdx.x;
  for (int j2 = tid; j2 < 6144; j2 += 256) {
    int j = j2 * 2;
    int bb = j / 384, kk = j - bb * 384;
    float2 v = ldx2(src + j);
    xs[bb * 385 + kk] = v.x; xs[bb * 385 + kk + 1] = v.y;
  }
}

// GEMV (G0): ncols cols of the job set, K=384 over 8 thread-groups of 48,
// shfl-pair -> 4 LDS partial rows (stride 33), chunked by 21 cols.
__device__ void gemv_run(const GJob* J, int cbase, int ncols, const float* xs, float* red) {
  const int tid = threadIdx.x;
  const int b = tid & 31, cg = tid >> 5;
  float xr[48];
  const float* xp = xs + b * 385 + cg * 48;
#pragma unroll
  for (int q = 0; q < 48; ++q) xr[q] = xp[q];
  for (int ch = 0; ch < ncols; ch += 21) {
    const int nch = min(21, ncols - ch);
    for (int ci = 0; ci < nch; ++ci) {
      const float* W; int ldw, koff; const float* bias; float* dst; int rstride; int cc;
      resolveJob(J, cbase + ch + ci, W, ldw, koff, bias, dst, rstride, cc);
      const float* wr = W + (size_t)cc * ldw + koff + cg * 48;
      float a = dot48(wr, xr);
      a += __shfl_down(a, 32, 64);
      if ((cg & 1) == 0) red[((cg >> 1) * nch + ci) * 33 + b] = a;
    }
    __syncthreads();
    const int pairs = nch * 32;
    for (int pi = tid; pi < pairs; pi += 256) {
      int bb = pi / nch, ci = pi - bb * nch;
      float s = red[(0 * nch + ci) * 33 + bb] + red[(1 * nch + ci) * 33 + bb]
              + red[(2 * nch + ci) * 33 + bb] + red[(3 * nch + ci) * 33 + bb];
      const float* W; int ldw, koff; const float* bias; float* dst; int rstride; int cc;
      resolveJob(J, cbase + ch + ci, W, ldw, koff, bias, dst, rstride, cc);
      if (bias) s += bias[cc];
      stx(dst + (size_t)bb * rstride + cc, s);
    }
    __syncthreads();
  }
}

// wave attention: klds holds the 384-dim key (LDS, wave-private); produces
// att[15] uniform in registers. 4 lanes per slot, 96 dims each.
__device__ __forceinline__ void wave_attn(const float* memh, const float* klds, const float* mgp,
                                          int t, int lane, float (&att)[15]) {
  const int g = lane >> 2, l = lane & 3;
  float part = 0.f;
  if (g < 15) {
    const float* mh = memh + ((t + g) % 15) * 384 + l;
#pragma unroll 8
    for (int k = 0; k < 96; ++k) part += mh[4 * k] * klds[l + 4 * k];
  }
  part += __shfl_xor(part, 1, 64);
  part += __shfl_xor(part, 2, 64);
  float logit[15];
#pragma unroll
  for (int s = 0; s < 15; ++s) logit[s] = __shfl(part, 4 * s, 64) * INV_SQRT_H;
  float m = logit[0];
#pragma unroll
  for (int s = 1; s < 15; ++s) m = fmaxf(m, logit[s]);
  float sum = 0.f;
#pragma unroll
  for (int s = 0; s < 15; ++s) { att[s] = expf(logit[s] - m) * mgp[s]; sum += att[s]; }
  float inv = 1.f / (sum + 1e-8f);
#pragma unroll
  for (int s = 0; s < 15; ++s) att[s] *= inv;
}

// ================= L0: one wave per b, local recurrence =================
__device__ void l0_loop(int b, int lane, float* xlds, float* klds, const ScanArgs& A, int* bar) {
  float* ws = A.ws;
  float* memh = ws + O_MEMH0 + (size_t)b * 5760;
  float* memc = ws + O_MEMC0 + (size_t)b * 5760;
  float* mir  = ws + O_P0 + (size_t)b * 23040;
  const int cs = lane >> 3, kg = lane & 7;
#pragma unroll
  for (int j = 0; j < 3; ++j)
    *(float2*)(klds + 2 * lane + 128 * j) = make_float2(0.f, 0.f);   // key_mh(t=0)=0
  for (int t = 0; t < 192; ++t) {
    const size_t tb = (size_t)t * 32 + b;
    float2 ih[12];
#pragma unroll
    for (int j = 0; j < 12; ++j)
      ih[j] = *(const float2*)(ws + O_IH0LN + tb * 1536 + 2 * lane + 128 * j);
    float2 kE[3];
#pragma unroll
    for (int j = 0; j < 3; ++j)
      kE[j] = *(const float2*)(ws + O_KEY0E + tb * 384 + 2 * lane + 128 * j);
    // lagged ring guard: G0(t-4) finished reading HNEW0 slot t%4
    if (lane < 32) {
      const int* fp = bar + F_G0 + lane;
      while (ldi(fp) < t - 3) __builtin_amdgcn_s_sleep(1);
    }
    // key = key_mh(prev step, klds) + KEY0E(t)
#pragma unroll
    for (int j = 0; j < 3; ++j) {
      float2 kv = *(float2*)(klds + 2 * lane + 128 * j);
      *(float2*)(klds + 2 * lane + 128 * j) = make_float2(kv.x + kE[j].x, kv.y + kE[j].y);
    }
    float att[15];
    wave_attn(memh, klds, ws + O_MG + tb * 15, t, lane, att);
    int pidx[15];
#pragma unroll
    for (int i = 0; i < 15; ++i) pidx[i] = (t + i) % 15;
    float2 acc[12];
#pragma unroll
    for (int j = 0; j < 12; ++j)
      acc[j] = *(const float2*)(A.r_bhh + 2 * lane + 128 * j);
#pragma unroll
    for (int s = 0; s < 15; ++s) {
      const float* P = mir + (size_t)pidx[s] * 1536;
      float a = att[s];
#pragma unroll
      for (int j = 0; j < 12; ++j) {
        float2 p = *(const float2*)(P + 2 * lane + 128 * j);
        acc[j].x += a * p.x; acc[j].y += a * p.y;
      }
    }
    float2 selc[3];
#pragma unroll
    for (int j = 0; j < 3; ++j) selc[j] = make_float2(0.f, 0.f);
#pragma unroll
    for (int s = 0; s < 15; ++s) {
      const float* C = memc + pidx[s] * 384;
      float a = att[s];
#pragma unroll
      for (int j = 0; j < 3; ++j) {
        float2 p = *(const float2*)(C + 2 * lane + 128 * j);
        selc[j].x += a * p.x; selc[j].y += a * p.y;
      }
    }
    // LN(ghh)
    float s1 = 0.f, s2 = 0.f;
#pragma unroll
    for (int j = 0; j < 12; ++j) {
      s1 += acc[j].x + acc[j].y;
      s2 += acc[j].x * acc[j].x + acc[j].y * acc[j].y;
    }
    float2 r = wred2(s1, s2);
    float mu = r.x * (1.f / 1536.f);
    float inv = 1.f / (sqrtf(fmaxf(r.y - r.x * mu, 0.f) * (1.f / 1535.f)) + 1e-6f);
    const float* hg = A.r_lnhh_g;
    const float* hb = A.r_lnhh_b;
    float2 cn[3], og[3];
#pragma unroll
    for (int jj = 0; jj < 3; ++jj) {
      const int d = 2 * lane + 128 * jj;
      float2 gi, gf, gc, go;
      { float2 g2 = *(const float2*)(hg + d), b2 = *(const float2*)(hb + d);
        gi.x = ih[jj].x + g2.x * (acc[jj].x - mu) * inv + b2.x;
        gi.y = ih[jj].y + g2.y * (acc[jj].y - mu) * inv + b2.y; }
      { float2 g2 = *(const float2*)(hg + 384 + d), b2 = *(const float2*)(hb + 384 + d);
        gf.x = ih[3 + jj].x + g2.x * (acc[3 + jj].x - mu) * inv + b2.x;
        gf.y = ih[3 + jj].y + g2.y * (acc[3 + jj].y - mu) * inv + b2.y; }
      { float2 g2 = *(const float2*)(hg + 768 + d), b2 = *(const float2*)(hb + 768 + d);
        gc.x = ih[6 + jj].x + g2.x * (acc[6 + jj].x - mu) * inv + b2.x;
        gc.y = ih[6 + jj].y + g2.y * (acc[6 + jj].y - mu) * inv + b2.y; }
      { float2 g2 = *(const float2*)(hg + 1152 + d), b2 = *(const float2*)(hb + 1152 + d);
        go.x = ih[9 + jj].x + g2.x * (acc[9 + jj].x - mu) * inv + b2.x;
        go.y = ih[9 + jj].y + g2.y * (acc[9 + jj].y - mu) * inv + b2.y; }
      cn[jj].x = sigmoidf(gf.x) * selc[jj].x + sigmoidf(gi.x) * tanhf(gc.x);
      cn[jj].y = sigmoidf(gf.y) * selc[jj].y + sigmoidf(gi.y) * tanhf(gc.y);
      og[jj] = go;
    }
    // LN(c)
    s1 = 0.f; s2 = 0.f;
#pragma unroll
    for (int jj = 0; jj < 3; ++jj) {
      s1 += cn[jj].x + cn[jj].y;
      s2 += cn[jj].x * cn[jj].x + cn[jj].y * cn[jj].y;
    }
    r = wred2(s1, s2);
    float mu_c = r.x * (1.f / 384.f);
    float inv_c = 1.f / (sqrtf(fmaxf(r.y - r.x * mu_c, 0.f) * (1.f / 383.f)) + 1e-6f);
    const int slot = t % 15;
#pragma unroll
    for (int jj = 0; jj < 3; ++jj) {
      const int d = 2 * lane + 128 * jj;
      float2 lg2 = *(const float2*)(A.r_lnc_g + d), lb2 = *(const float2*)(A.r_lnc_b + d);
      float2 hn;
      hn.x = sigmoidf(og[jj].x) * tanhf(lg2.x * (cn[jj].x - mu_c) * inv_c + lb2.x);
      hn.y = sigmoidf(og[jj].y) * tanhf(lg2.y * (cn[jj].y - mu_c) * inv_c + lb2.y);
      *(float2*)(memh + slot * 384 + d) = hn;
      *(float2*)(memc + slot * 384 + d) = cn[jj];
      *(float2*)(xlds + d) = hn;
      stx2(ws + O_HNEW0R + (size_t)(t & 3) * 12288 + (size_t)b * 384 + d, hn);
    }
    // ---- local GEMVs from h_new (xlds): fresh P (1536) + key_mh (384) ----
    float xr[48];
    {
      const float* xp = xlds + kg * 48;
#pragma unroll
      for (int q = 0; q < 48; ++q) xr[q] = xp[q];
    }
    float* mirP = mir + (size_t)slot * 1536;
#pragma unroll 2
    for (int p = 0; p < 192; ++p) {
      const float* wr = A.r_whh + (size_t)(p * 8 + cs) * 384 + kg * 48;
      float a = red8(dot48(wr, xr));
      if (kg == 0) mirP[p * 8 + cs] = a;
    }
#pragma unroll 2
    for (int p = 0; p < 48; ++p) {
      const float* wr = A.r_proj_w + (size_t)(p * 8 + cs) * 768 + 384 + kg * 48;
      float a = red8(dot48(wr, xr));
      if (kg == 0) klds[p * 8 + cs] = a;
    }
    asm volatile("s_waitcnt vmcnt(0)" ::: "memory");
    if (lane == 0) sti(bar + F_L0 + b, t + 1);
  }
}

// ================= L1: one wave per b, local recurrence =================
__device__ void l1_loop(int b, int lane, float* xlds, float* klds, const ScanArgs& A, int* bar) {
  float* ws = A.ws;
  float* memh = ws + O_MEMH1 + (size_t)b * 5760;
  float* memc = ws + O_MEMC1 + (size_t)b * 5760;
  float* mir  = ws + O_P1 + (size_t)b * 23040;
  const float* hg = A.r_lnhh_g + 1536;
  const float* hb = A.r_lnhh_b + 1536;
  const float* igp = A.r_lnih_g + 1536;
  const float* ibp = A.r_lnih_b + 1536;
  const float* bhh = A.r_bhh + 1536;
  const float* lcg = A.r_lnc_g + 384;
  const float* lcb = A.r_lnc_b + 384;
  const int cs = lane >> 3, kg = lane & 7;
#pragma unroll
  for (int j = 0; j < 3; ++j)
    *(float2*)(klds + 2 * lane + 128 * j) = make_float2(0.f, 0.f);
  for (int t = 0; t < 192; ++t) {
    // waits: G0(t) done (all 32) ; PR(t-4) done reading HNEW1 slot t%4
    if (lane < 33) {
      const int* fp = (lane < 32) ? (bar + F_G0 + lane) : (bar + F_PR + b);
      const int tgt = (lane < 32) ? (t + 1) : (t - 3);
      while (ldi(fp) < tgt) __builtin_amdgcn_s_sleep(1);
    }
    const size_t tb = (size_t)t * 32 + b;
    const size_t rs = (size_t)(t & 3);
    float2 gx[12];
#pragma unroll
    for (int j = 0; j < 12; ++j)
      gx[j] = ldx2(ws + O_IH1RAWR + rs * 49152 + (size_t)b * 1536 + 2 * lane + 128 * j);
#pragma unroll
    for (int j = 0; j < 3; ++j) {
      float2 kh = ldx2(ws + O_KEY1HR + rs * 12288 + (size_t)b * 384 + 2 * lane + 128 * j);
      float2 kv = *(float2*)(klds + 2 * lane + 128 * j);
      *(float2*)(klds + 2 * lane + 128 * j) = make_float2(kv.x + kh.x, kv.y + kh.y);
    }
    float att[15];
    wave_attn(memh, klds, ws + O_MG + tb * 15, t, lane, att);
    int pidx[15];
#pragma unroll
    for (int i = 0; i < 15; ++i) pidx[i] = (t + i) % 15;
    float2 acc[12];
#pragma unroll
    for (int j = 0; j < 12; ++j)
      acc[j] = *(const float2*)(bhh + 2 * lane + 128 * j);
#pragma unroll
    for (int s = 0; s < 15; ++s) {
      const float* P = mir + (size_t)pidx[s] * 1536;
      float a = att[s];
#pragma unroll
      for (int j = 0; j < 12; ++j) {
        float2 p = *(const float2*)(P + 2 * lane + 128 * j);
        acc[j].x += a * p.x; acc[j].y += a * p.y;
      }
    }
    float2 selc[3];
#pragma unroll
    for (int j = 0; j < 3; ++j) selc[j] = make_float2(0.f, 0.f);
#pragma unroll
    for (int s = 0; s < 15; ++s) {
      const float* C = memc + pidx[s] * 384;
      float a = att[s];
#pragma unroll
      for (int j = 0; j < 3; ++j) {
        float2 p = *(const float2*)(C + 2 * lane + 128 * j);
        selc[j].x += a * p.x; selc[j].y += a * p.y;
      }
    }
    // LN(gih)
    float s1 = 0.f, s2 = 0.f;
#pragma unroll
    for (int j = 0; j < 12; ++j) {
      s1 += gx[j].x + gx[j].y;
      s2 += gx[j].x * gx[j].x + gx[j].y * gx[j].y;
    }
    float2 r = wred2(s1, s2);
    float mu_i = r.x * (1.f / 1536.f);
    float inv_i = 1.f / (sqrtf(fmaxf(r.y - r.x * mu_i, 0.f) * (1.f / 1535.f)) + 1e-6f);
    // LN(ghh)
    s1 = 0.f; s2 = 0.f;
#pragma unroll
    for (int j = 0; j < 12; ++j) {
      s1 += acc[j].x + acc[j].y;
      s2 += acc[j].x * acc[j].x + acc[j].y * acc[j].y;
    }
    r = wred2(s1, s2);
    float mu = r.x * (1.f / 1536.f);
    float inv = 1.f / (sqrtf(fmaxf(r.y - r.x * mu, 0.f) * (1.f / 1535.f)) + 1e-6f);
    float2 cn[3], og[3];
#pragma unroll
    for (int jj = 0; jj < 3; ++jj) {
      const int d = 2 * lane + 128 * jj;
      float2 gi, gf, gc, go;
      { float2 i2 = *(const float2*)(igp + d), ib2 = *(const float2*)(ibp + d);
        float2 g2 = *(const float2*)(hg + d), b2 = *(const float2*)(hb + d);
        gi.x = i2.x * (gx[jj].x - mu_i) * inv_i + ib2.x + g2.x * (acc[jj].x - mu) * inv + b2.x;
        gi.y = i2.y * (gx[jj].y - mu_i) * inv_i + ib2.y + g2.y * (acc[jj].y - mu) * inv + b2.y; }
      { float2 i2 = *(const float2*)(igp + 384 + d), ib2 = *(const float2*)(ibp + 384 + d);
        float2 g2 = *(const float2*)(hg + 384 + d), b2 = *(const float2*)(hb + 384 + d);
        gf.x = i2.x * (gx[3 + jj].x - mu_i) * inv_i + ib2.x + g2.x * (acc[3 + jj].x - mu) * inv + b2.x;
        gf.y = i2.y * (gx[3 + jj].y - mu_i) * inv_i + ib2.y + g2.y * (acc[3 + jj].y - mu) * inv + b2.y; }
      { float2 i2 = *(const float2*)(igp + 768 + d), ib2 = *(const float2*)(ibp + 768 + d);
        float2 g2 = *(const float2*)(hg + 768 + d), b2 = *(const float2*)(hb + 768 + d);
        gc.x = i2.x * (gx[6 + jj].x - mu_i) * inv_i + ib2.x + g2.x * (acc[6 + jj].x - mu) * inv + b2.x;
        gc.y = i2.y * (gx[6 + jj].y - mu_i) * inv_i + ib2.y + g2.y * (acc[6 + jj].y - mu) * inv + b2.y; }
      { float2 i2 = *(const float2*)(igp + 1152 + d), ib2 = *(const float2*)(ibp + 1152 + d);
        float2 g2 = *(const float2*)(hg + 1152 + d), b2 = *(const float2*)(hb + 1152 + d);
        go.x = i2.x * (gx[9 + jj].x - mu_i) * inv_i + ib2.x + g2.x * (acc[9 + jj].x - mu) * inv + b2.x;
        go.y = i2.y * (gx[9 + jj].y - mu_i) * inv_i + ib2.y + g2.y * (acc[9 + jj].y - mu) * inv + b2.y; }
      cn[jj].x = sigmoidf(gf.x) * selc[jj].x + sigmoidf(gi.x) * tanhf(gc.x);
      cn[jj].y = sigmoidf(gf.y) * selc[jj].y + sigmoidf(gi.y) * tanhf(gc.y);
      og[jj] = go;
    }
    s1 = 0.f; s2 = 0.f;
#pragma unroll
    for (int jj = 0; jj < 3; ++jj) {
      s1 += cn[jj].x + cn[jj].y;
      s2 += cn[jj].x * cn[jj].x + cn[jj].y * cn[jj].y;
    }
    r = wred2(s1, s2);
    float mu_c = r.x * (1.f / 384.f);
    float inv_c = 1.f / (sqrtf(fmaxf(r.y - r.x * mu_c, 0.f) * (1.f / 383.f)) + 1e-6f);
    const int slot = t % 15;
#pragma unroll
    for (int jj = 0; jj < 3; ++jj) {
      const int d = 2 * lane + 128 * jj;
      float2 lg2 = *(const float2*)(lcg + d), lb2 = *(const float2*)(lcb + d);
      float2 hn;
      hn.x = sigmoidf(og[jj].x) * tanhf(lg2.x * (cn[jj].x - mu_c) * inv_c + lb2.x);
      hn.y = sigmoidf(og[jj].y) * tanhf(lg2.y * (cn[jj].y - mu_c) * inv_c + lb2.y);
      *(float2*)(memh + slot * 384 + d) = hn;
      *(float2*)(memc + slot * 384 + d) = cn[jj];
      *(float2*)(xlds + d) = hn;
      *(float2*)(ws + O_OUTHS + tb * 768 + d) = hn;
      stx2(ws + O_HNEW1R + rs * 12288 + (size_t)b * 384 + d, hn);
    }
    // ---- local GEMVs: fresh P1 (whh1) + key_mh1 (proj1mh) ----
    float xr[48];
    {
      const float* xp = xlds + kg * 48;
#pragma unroll
      for (int q = 0; q < 48; ++q) xr[q] = xp[q];
    }
    float* mirP = mir + (size_t)slot * 1536;
#pragma unroll 2
    for (int p = 0; p < 192; ++p) {
      const float* wr = A.r_whh + 589824 + (size_t)(p * 8 + cs) * 384 + kg * 48;
      float a = red8(dot48(wr, xr));
      if (kg == 0) mirP[p * 8 + cs] = a;
    }
#pragma unroll 2
    for (int p = 0; p < 48; ++p) {
      const float* wr = A.r_proj_w + (size_t)(384 + p * 8 + cs) * 768 + 384 + kg * 48;
      float a = red8(dot48(wr, xr));
      if (kg == 0) klds[p * 8 + cs] = a;
    }
    asm volatile("s_waitcnt vmcnt(0)" ::: "memory");
    if (lane == 0) sti(bar + F_L1 + b, t + 1);
  }
}

// ================= PR: one wave per b, local pkey =================
__device__ void pr_loop(int b, int lane, float* xx /*768*/, float* pk /*384*/,
                        const ScanArgs& A, int* bar) {
  float* ws = A.ws;
  float* pmem = ws + O_PMEM + (size_t)b * 5760;
  const int cs = lane >> 3, kg = lane & 7;
#pragma unroll
  for (int j = 0; j < 3; ++j)
    *(float2*)(xx + 384 + 2 * lane + 128 * j) = make_float2(0.f, 0.f);  // h1(-1)=0
  for (int t = 0; t < 192; ++t) {
    {
      const int* fp = bar + F_L1 + b;       // uniform poll (same address all lanes)
      while (ldi(fp) < t + 1) __builtin_amdgcn_s_sleep(1);
    }
    const size_t tb = (size_t)t * 32 + b;
    float2 h1t[3];
#pragma unroll
    for (int j = 0; j < 3; ++j) {
      h1t[j] = ldx2(ws + O_HNEW1R + (size_t)(t & 3) * 12288 + (size_t)b * 384 + 2 * lane + 128 * j);
      *(float2*)(xx + 2 * lane + 128 * j) = h1t[j];
    }
    // pkey = pproj_h @ h1(t) + pproj_m @ h1(t-1) + bias
    float xrA[48], xrB[48];
    {
      const float* xpA = xx + kg * 48;
      const float* xpB = xx + 384 + kg * 48;
#pragma unroll
      for (int q = 0; q < 48; ++q) { xrA[q] = xpA[q]; xrB[q] = xpB[q]; }
    }
#pragma unroll 2
    for (int p = 0; p < 48; ++p) {
      const int col = p * 8 + cs;
      const float* wr = A.p_proj_w + (size_t)col * 768 + kg * 48;
      float a = dot48(wr, xrA) + dot48(wr + 384, xrB);
      a = red8(a);
      if (kg == 0) pk[col] = a + A.p_proj_b[col];
    }
    float att[15];
    wave_attn(pmem, pk, ws + O_MGN + tb * 15, t, lane, att);
    int pidx[15];
#pragma unroll
    for (int i = 0; i < 15; ++i) pidx[i] = (t + i) % 15;
    float2 sel[3];
#pragma unroll
    for (int j = 0; j < 3; ++j) sel[j] = make_float2(0.f, 0.f);
#pragma unroll
    for (int s = 0; s < 15; ++s) {
      const float* P = pmem + pidx[s] * 384;
      float a = att[s];
#pragma unroll
      for (int j = 0; j < 3; ++j) {
        float2 p = *(const float2*)(P + 2 * lane + 128 * j);
        sel[j].x += a * p.x; sel[j].y += a * p.y;
      }
    }
#pragma unroll
    for (int j = 0; j < 3; ++j) {
      const int d = 2 * lane + 128 * j;
      *(float2*)(ws + O_OUTHS + tb * 768 + 384 + d) = sel[j];
      *(float2*)(pmem + (t % 15) * 384 + d) = h1t[j];     // append after reads
      *(float2*)(xx + 384 + d) = h1t[j];                  // becomes h1(t-1)
    }
    if (lane == 0) sti(bar + F_PR + b, t + 1);
  }
}

// ================= G0: feed-forward wih1/proj1h from h0(t) =================
__device__ void g0_loop(int gwg, const ScanArgs& A, int* bar, float* sm) {
  float* ws = A.ws;
  const int tid = threadIdx.x;
  float* xs = sm;
  float* red = sm + 12320;
  const int c0 = gwg * 60;                // 1920 cols over 32 wgs
  for (int t = 0; t < 192; ++t) {
    if (tid < 64) {
      const int* fp = (tid < 32) ? (bar + F_L0 + tid) : (bar + F_L1 + (tid - 32));
      const int tgt = (tid < 32) ? (t + 1) : (t - 3);
      while (ldi(fp) < tgt) __builtin_amdgcn_s_sleep(1);
    }
    __syncthreads();
    const size_t rs = (size_t)(t & 3);
    stage_x(ws + O_HNEW0R + rs * 12288, xs);
    __syncthreads();
    GJob J[2] = {
      { A.r_wih + 589824, 384, 0, A.r_bih + 1536, ws + O_IH1RAWR + rs * 49152, 1536, 1536 },
      { A.r_proj_w + 294912, 768, 0, A.r_proj_b + 384, ws + O_KEY1HR + rs * 12288, 384, 384 },
    };
    gemv_run(J, c0, 60, xs, red);         // ends with __syncthreads (drains stx)
    if (tid == 0) sti(bar + F_G0 + gwg, t + 1);
  }
}

// grid: 8 L0 | 8 L1 | 8 PR | 32 G0 = 56 wgs
__global__ __launch_bounds__(256) void k_scan(ScanArgs A) {
  __shared__ float sm[15104];   // G0: xs 12320 + red 2772 | L: 4x(x 384 + k 384) | PR: 4x(xx 768 + pk 384)
  int* bar = (int*)(A.ws + O_BAR);
  const int wg = blockIdx.x;
  const int tid = threadIdx.x;
  const int lane = tid & 63;
  const int wv = tid >> 6;
  if (wg < 8)        l0_loop(wg * 4 + wv, lane, sm + wv * 768, sm + wv * 768 + 384, A, bar);
  else if (wg < 16)  l1_loop((wg - 8) * 4 + wv, lane, sm + wv * 768, sm + wv * 768 + 384, A, bar);
  else if (wg < 24)  pr_loop((wg - 16) * 4 + wv, lane, sm + wv * 1152, sm + wv * 1152 + 768, A, bar);
  else               g0_loop(wg - 24, A, bar, sm);
}

// ---------------------------------------------------------------- launch
extern "C" void kernel_launch(void* const* d_in, const int* in_sizes, int n_in,
                              void* d_out, int out_size, void* d_ws, size_t ws_size,
                              hipStream_t stream) {
  const int* ids = (const int*)d_in[0];
  const float* emb_w = (const float*)d_in[1];
  const float* pconv1_w = (const float*)d_in[2];
  const float* pconv1_b = (const float*)d_in[3];
  const float* pbn_g = (const float*)d_in[4];
  const float* pbn_b = (const float*)d_in[5];
  const float* pconv2_w = (const float*)d_in[6];
  const float* pconv2_b = (const float*)d_in[7];
  const float* r_wih = (const float*)d_in[8];
  const float* r_bih = (const float*)d_in[9];
  const float* r_whh = (const float*)d_in[10];
  const float* r_bhh = (const float*)d_in[11];
  const float* r_lnih_g = (const float*)d_in[12];
  const float* r_lnih_b = (const float*)d_in[13];
  const float* r_lnhh_g = (const float*)d_in[14];
  const float* r_lnhh_b = (const float*)d_in[15];
  const float* r_lnc_g = (const float*)d_in[16];
  const float* r_lnc_b = (const float*)d_in[17];
  const float* r_proj_w = (const float*)d_in[18];
  const float* r_proj_b = (const float*)d_in[19];
  const float* p_proj_w = (const float*)d_in[20];
  const float* p_proj_b = (const float*)d_in[21];
  const float* p_ffd_w = (const float*)d_in[22];
  const float* p_ffd_b = (const float*)d_in[23];
  const float* p_bn_g = (const float*)d_in[24];
  const float* p_bn_b = (const float*)d_in[25];
  float* ws = (float*)d_ws;
  float* out = (float*)d_out;

  k_zero<<<1024, 256, 0, stream>>>(ws + O_MEMH0, (int)(O_STATEEND - O_MEMH0));
  k_emb<<<4096, 256, 0, stream>>>(ids, emb_w, ws + O_EMB, out);
  k_conv<<<dim3(6, 96), 256, 0, stream>>>(ws + O_EMB, pconv1_w, pconv1_b, pbn_g, pbn_b, ws + O_H1);
  k_gate<<<6144, 256, 0, stream>>>(ws + O_H1, pconv2_w, pconv2_b, ws + O_GATEA, ws + O_GATEB);
  k_mg<<<24, 256, 0, stream>>>(ws + O_GATEA, ws + O_GATEB, ws + O_MG, ws + O_MGN);
  // rings + flags live in the (now dead) conv-activation region
  k_zero<<<338, 256, 0, stream>>>(ws + O_HNEW0R, (int)(O_DEADEND - O_HNEW0R));
  // precompute LN(e@Wih0+b) and key0_e = e@proj0_h + b for all t
  k_gemm<<<dim3(24, 96), 256, 0, stream>>>(ws + O_EMB, 384, r_wih, 384, r_bih,
                                           ws + O_IH0LN, 1536, 384, 0, nullptr, nullptr, nullptr);
  k_gemm<<<dim3(6, 96), 256, 0, stream>>>(ws + O_EMB, 384, r_proj_w, 768, r_proj_b,
                                          ws + O_KEY0E, 384, 384, 0, nullptr, nullptr, nullptr);
  k_ln_rows<<<6144, 256, 0, stream>>>(ws + O_IH0LN, r_lnih_g, r_lnih_b);
  ScanArgs SA{ws, r_whh, r_bhh, r_lnhh_g, r_lnhh_b, r_lnih_g, r_lnih_b,
              r_lnc_g, r_lnc_b, r_wih, r_bih, r_proj_w, r_proj_b, p_proj_w, p_proj_b};
  k_scan<<<56, 256, 0, stream>>>(SA);
  // head: y = tanh(BN(flat @ p_ffd^T + b)) -> out
  k_gemm<<<dim3(6, 96), 256, 0, stream>>>(ws + O_OUTHS, 768, p_ffd_w, 768, p_ffd_b,
                                          nullptr, 384, 768, 1, p_bn_g, p_bn_b, out);
}